// Round 2
// baseline (22710.341 us; speedup 1.0000x reference)
//
#include <hip/hip_runtime.h>
#include <hip/hip_bf16.h>
#include <math.h>

#define EPS 1e-5f

// ---------------- backbone: direct 3x3 stride-2 pad-1 conv + bias ----------------
__global__ __launch_bounds__(256) void conv3x3_s2_k(const float* __restrict__ in,
                                                    const float* __restrict__ w,
                                                    const float* __restrict__ bias,
                                                    float* __restrict__ out,
                                                    int Cin, int Cout, int Hin, int Win)
{
    int Hout = Hin >> 1, Wout = Win >> 1;
    int total = Cout * Hout * Wout;
    int idx = blockIdx.x * blockDim.x + threadIdx.x;
    if (idx >= total) return;
    int wo = idx % Wout;
    int t  = idx / Wout;
    int ho = t % Hout;
    int co = t / Hout;
    float acc = bias[co];
    int hi0 = ho * 2 - 1, wi0 = wo * 2 - 1;
    const float* wp = w + (long)co * Cin * 9;
    for (int ci = 0; ci < Cin; ci++) {
        const float* ip = in + (long)ci * Hin * Win;
        const float* wc = wp + ci * 9;
        #pragma unroll
        for (int kh = 0; kh < 3; kh++) {
            int hi = hi0 + kh;
            if (hi < 0 || hi >= Hin) continue;
            #pragma unroll
            for (int kw = 0; kw < 3; kw++) {
                int wi = wi0 + kw;
                if (wi < 0 || wi >= Win) continue;
                acc += ip[(long)hi * Win + wi] * wc[kh * 3 + kw];
            }
        }
    }
    out[idx] = acc;
}

// ---------------- GroupNorm (CHW layout, channels contiguous per group) ----------------
__global__ __launch_bounds__(256) void gn_stats_k(const float* __restrict__ x, long grpLen,
                                                  float* __restrict__ stats)
{
    int g = blockIdx.x;
    const float* p = x + (long)g * grpLen;
    float s = 0.f, s2 = 0.f;
    for (long i = threadIdx.x; i < grpLen; i += blockDim.x) {
        float v = p[i];
        s += v; s2 += v * v;
    }
    __shared__ float rs[256], rq[256];
    rs[threadIdx.x] = s; rq[threadIdx.x] = s2;
    __syncthreads();
    for (int o = 128; o > 0; o >>= 1) {
        if (threadIdx.x < o) { rs[threadIdx.x] += rs[threadIdx.x + o]; rq[threadIdx.x] += rq[threadIdx.x + o]; }
        __syncthreads();
    }
    if (threadIdx.x == 0) {
        float mean = rs[0] / (float)grpLen;
        float var  = rq[0] / (float)grpLen - mean * mean;
        stats[g * 2]     = mean;
        stats[g * 2 + 1] = rsqrtf(var + EPS);
    }
}

__global__ __launch_bounds__(256) void gn_apply_k(float* __restrict__ x,
                                                  const float* __restrict__ gamma,
                                                  const float* __restrict__ beta,
                                                  const float* __restrict__ stats,
                                                  int HW, int cpg, int total, int relu)
{
    int idx = blockIdx.x * blockDim.x + threadIdx.x;
    if (idx >= total) return;
    int c = idx / HW;
    int g = c / cpg;
    float v = (x[idx] - stats[g * 2]) * stats[g * 2 + 1] * gamma[c] + beta[c];
    if (relu) v = fmaxf(v, 0.f);
    x[idx] = v;
}

// ---------------- GroupNorm for feats in HWD layout (1400 x 256 per cam, cpg=8) ----------------
__global__ __launch_bounds__(256) void gn_stats_hwd_k(const float* __restrict__ x, float* __restrict__ stats)
{
    int g = blockIdx.x;  // 32 groups
    float s = 0.f, s2 = 0.f;
    for (int i = threadIdx.x; i < 1400 * 8; i += blockDim.x) {
        int p = i >> 3, c = g * 8 + (i & 7);
        float v = x[(long)p * 256 + c];
        s += v; s2 += v * v;
    }
    __shared__ float rs[256], rq[256];
    rs[threadIdx.x] = s; rq[threadIdx.x] = s2;
    __syncthreads();
    for (int o = 128; o > 0; o >>= 1) {
        if (threadIdx.x < o) { rs[threadIdx.x] += rs[threadIdx.x + o]; rq[threadIdx.x] += rq[threadIdx.x + o]; }
        __syncthreads();
    }
    if (threadIdx.x == 0) {
        float mean = rs[0] / 11200.f;
        float var  = rq[0] / 11200.f - mean * mean;
        stats[g * 2]     = mean;
        stats[g * 2 + 1] = rsqrtf(var + EPS);
    }
}

__global__ __launch_bounds__(256) void gn_apply_hwd_k(float* __restrict__ x,
                                                      const float* __restrict__ gamma,
                                                      const float* __restrict__ beta,
                                                      const float* __restrict__ stats)
{
    int idx = blockIdx.x * blockDim.x + threadIdx.x;  // 1400*256
    if (idx >= 1400 * 256) return;
    int c = idx & 255;
    int g = c >> 3;
    x[idx] = (x[idx] - stats[g * 2]) * stats[g * 2 + 1] * gamma[c] + beta[c];
}

// ---------------- generic tiled GEMM: C[M,N] = A(MxK, strided) @ B(KxN, strided) ----------------
// epilogue: + bias, optional exact-GELU (act==2), optional residual add (fp32)
__global__ __launch_bounds__(256) void gemm_k(const float* __restrict__ A, long a_rs, long a_ks,
                                              const float* __restrict__ B, long b_ks, long b_ns,
                                              const float* __restrict__ bias,
                                              const float* __restrict__ resid,
                                              float* __restrict__ C,
                                              int M, int N, int K, int act)
{
    __shared__ float As[16][65];
    __shared__ float Bs[16][65];
    int tid = threadIdx.x;
    int tx = tid & 15, ty = tid >> 4;
    int m0 = blockIdx.y * 64, n0 = blockIdx.x * 64;
    float acc[4][4] = {{0.f}};
    for (int kt = 0; kt < K; kt += 16) {
        #pragma unroll
        for (int u = 0; u < 4; u++) {
            int e  = tid * 4 + u;          // 0..1023
            int ka = e & 15, mm = e >> 4;  // A: 64 rows x 16 k
            int gm = m0 + mm;
            As[ka][mm] = (gm < M) ? A[(long)gm * a_rs + (long)(kt + ka) * a_ks] : 0.f;
            int nn = e & 63, kb = e >> 6;  // B: 16 k x 64 cols
            Bs[kb][nn] = B[(long)(kt + kb) * b_ks + (long)(n0 + nn) * b_ns];
        }
        __syncthreads();
        #pragma unroll
        for (int kk = 0; kk < 16; kk++) {
            float av[4], bv[4];
            #pragma unroll
            for (int i = 0; i < 4; i++) av[i] = As[kk][ty * 4 + i];
            #pragma unroll
            for (int j = 0; j < 4; j++) bv[j] = Bs[kk][tx * 4 + j];
            #pragma unroll
            for (int i = 0; i < 4; i++)
                #pragma unroll
                for (int j = 0; j < 4; j++)
                    acc[i][j] += av[i] * bv[j];
        }
        __syncthreads();
    }
    #pragma unroll
    for (int i = 0; i < 4; i++) {
        int r = m0 + ty * 4 + i;
        if (r >= M) continue;
        #pragma unroll
        for (int j = 0; j < 4; j++) {
            int cn = n0 + tx * 4 + j;
            float v = acc[i][j];
            if (bias) v += bias[cn];
            if (act == 2) v = 0.5f * v * (1.f + erff(v * 0.70710678118654752f));
            if (resid) v += resid[(long)r * N + cn];
            C[(long)r * N + cn] = v;
        }
    }
}

// ---------------- projection of BEV grid into cameras ----------------
__global__ __launch_bounds__(256) void project_k(const float* __restrict__ Kin,
                                                 const float* __restrict__ Ein,
                                                 float* __restrict__ refp, int* __restrict__ valid)
{
    int idx = blockIdx.x * blockDim.x + threadIdx.x;
    if (idx >= 2500 * 6) return;
    int c = idx % 6, q = idx / 6;
    int i = q / 50, j = q % 50;
    float px = (i - 24.5f) * 0.5f;
    float py = (j - 24.5f) * 0.5f;
    const float* E = Ein + c * 16;
    float pc[4];
    #pragma unroll
    for (int r = 0; r < 4; r++)
        pc[r] = E[r * 4 + 0] * px + E[r * 4 + 1] * py + E[r * 4 + 3];
    const float* Km = Kin + c * 9;
    float pix[3];
    #pragma unroll
    for (int r = 0; r < 3; r++)
        pix[r] = Km[r * 3 + 0] * pc[0] + Km[r * 3 + 1] * pc[1] + Km[r * 3 + 2] * pc[2];
    float z = fmaxf(pix[2], 1e-5f);
    float u = pix[0] / z, v = pix[1] / z;
    int ok = (pc[2] > 0.f) && (u >= 0.f) && (u < 800.f) && (v >= 0.f) && (v < 448.f);
    refp[(long)idx * 2 + 0] = 2.f * u / 799.f - 1.f;
    refp[(long)idx * 2 + 1] = 2.f * v / 447.f - 1.f;
    valid[idx] = ok;
}

// ---------------- misc elementwise ----------------
__global__ __launch_bounds__(256) void qinit_k(const float* __restrict__ a, const float* __restrict__ b,
                                               float* __restrict__ y)
{
    int i = blockIdx.x * blockDim.x + threadIdx.x;
    if (i >= 2500 * 256) return;
    y[i] = a[i] + b[i];
}

// ---------------- LayerNorm: one wave per row of 256 ----------------
__global__ __launch_bounds__(256) void ln_k(const float* __restrict__ x,
                                            const float* __restrict__ g, const float* __restrict__ b,
                                            float* __restrict__ y)
{
    int row  = blockIdx.x * 4 + (threadIdx.x >> 6);
    int lane = threadIdx.x & 63;
    if (row >= 2500) return;
    const float* xp = x + (long)row * 256;
    float v[4];
    #pragma unroll
    for (int i = 0; i < 4; i++) v[i] = xp[lane + 64 * i];
    float s  = v[0] + v[1] + v[2] + v[3];
    float s2 = v[0] * v[0] + v[1] * v[1] + v[2] * v[2] + v[3] * v[3];
    #pragma unroll
    for (int o = 32; o > 0; o >>= 1) { s += __shfl_xor(s, o, 64); s2 += __shfl_xor(s2, o, 64); }
    float mean = s * (1.f / 256.f);
    float var  = s2 * (1.f / 256.f) - mean * mean;
    float rstd = rsqrtf(var + EPS);
    #pragma unroll
    for (int i = 0; i < 4; i++) {
        int cc = lane + 64 * i;
        y[(long)row * 256 + cc] = (v[i] - mean) * rstd * g[cc] + b[cc];
    }
}

// ---------------- flash-style MHA: one wave per (query, head), hd=32, 2500 keys ----------------
__global__ __launch_bounds__(64) void flash_k(const float* __restrict__ Q, const float* __restrict__ Km,
                                              const float* __restrict__ V, float* __restrict__ O)
{
    int q = blockIdx.x, h = blockIdx.y, lane = threadIdx.x;
    const float scale = 0.17677669529663687f;  // 1/sqrt(32)
    float qv[32];
    const float* qp = Q + (long)q * 256 + h * 32;
    #pragma unroll
    for (int d = 0; d < 32; d++) qv[d] = qp[d] * scale;
    float m = -INFINITY, lsum = 0.f;
    float oacc[32];
    #pragma unroll
    for (int d = 0; d < 32; d++) oacc[d] = 0.f;
    for (int base = 0; base < 2500; base += 64) {
        int j = base + lane;
        bool act = j < 2500;
        float s = -INFINITY;
        if (act) {
            const float* kp = Km + (long)j * 256 + h * 32;
            float a = 0.f;
            #pragma unroll
            for (int d = 0; d < 32; d++) a += qv[d] * kp[d];
            s = a;
        }
        float cm = s;
        #pragma unroll
        for (int o = 32; o > 0; o >>= 1) cm = fmaxf(cm, __shfl_xor(cm, o, 64));
        float mn = fmaxf(m, cm);
        float alpha = expf(m - mn);  // m=-inf initially -> 0
        lsum *= alpha;
        #pragma unroll
        for (int d = 0; d < 32; d++) oacc[d] *= alpha;
        if (act) {
            float p = expf(s - mn);
            lsum += p;
            const float* vp = V + (long)j * 256 + h * 32;
            #pragma unroll
            for (int d = 0; d < 32; d++) oacc[d] += p * vp[d];
        }
        m = mn;
    }
    #pragma unroll
    for (int o = 32; o > 0; o >>= 1) lsum += __shfl_xor(lsum, o, 64);
    __shared__ float red[64][33];
    #pragma unroll
    for (int d = 0; d < 32; d++) red[lane][d] = oacc[d];
    __syncthreads();
    if (lane < 32) {
        float tot = 0.f;
        for (int jj = 0; jj < 64; jj++) tot += red[jj][lane];
        O[(long)q * 256 + h * 32 + lane] = tot / lsum;
    }
}

// ---------------- masked softmax over 192 deformable-attn logits per query ----------------
__global__ __launch_bounds__(64) void scasoftmax_k(float* __restrict__ logits, const int* __restrict__ valid)
{
    int q = blockIdx.x, lane = threadIdx.x;
    float v[3]; int mk[3];
    #pragma unroll
    for (int i = 0; i < 3; i++) {
        int idx = i * 64 + lane;
        int c = idx >> 5;
        mk[i] = valid[q * 6 + c];
        v[i] = mk[i] ? logits[(long)q * 192 + idx] : -1e30f;
    }
    float mx = fmaxf(fmaxf(v[0], v[1]), v[2]);
    #pragma unroll
    for (int o = 32; o > 0; o >>= 1) mx = fmaxf(mx, __shfl_xor(mx, o, 64));
    float e[3]; float s = 0.f;
    #pragma unroll
    for (int i = 0; i < 3; i++) { e[i] = expf(v[i] - mx); s += e[i]; }
    #pragma unroll
    for (int o = 32; o > 0; o >>= 1) s += __shfl_xor(s, o, 64);
    float inv = 1.f / s;
    #pragma unroll
    for (int i = 0; i < 3; i++)
        logits[(long)q * 192 + i * 64 + lane] = mk[i] ? e[i] * inv : 0.f;
}

// ---------------- deformable sampling: block per query, thread per channel ----------------
__global__ __launch_bounds__(256) void sample_k(const float* __restrict__ vals,  // (6,1400,256) hwd
                                                const float* __restrict__ offs,  // (2500,384)
                                                const float* __restrict__ wts,   // (2500,192)
                                                const float* __restrict__ refp,  // (2500,6,2)
                                                const int* __restrict__ valid,   // (2500,6)
                                                float* __restrict__ out)         // (2500,256)
{
    int q = blockIdx.x, d = threadIdx.x;
    __shared__ float s_cw[32][4];
    __shared__ int   s_idx[32][4];
    float acc = 0.f;
    for (int c = 0; c < 6; c++) {
        if (!valid[q * 6 + c]) continue;  // block-uniform branch
        __syncthreads();
        if (d < 32) {
            float ox = offs[(long)q * 384 + (c * 32 + d) * 2 + 0];
            float oy = offs[(long)q * 384 + (c * 32 + d) * 2 + 1];
            float px = refp[(q * 6 + c) * 2 + 0] + ox * (2.f / 49.f);
            float py = refp[(q * 6 + c) * 2 + 1] + oy * (2.f / 27.f);
            float gx = (px + 1.f) * 0.5f * 49.f;
            float gy = (py + 1.f) * 0.5f * 27.f;
            float x0f = floorf(gx), y0f = floorf(gy);
            float wx = gx - x0f, wy = gy - y0f;
            int x0 = (int)x0f, y0 = (int)y0f;
            float wgt = wts[(long)q * 192 + c * 32 + d];
            float cw[4] = {(1.f - wx) * (1.f - wy), wx * (1.f - wy), (1.f - wx) * wy, wx * wy};
            const int dxs[4] = {0, 1, 0, 1};
            const int dys[4] = {0, 0, 1, 1};
            #pragma unroll
            for (int k2 = 0; k2 < 4; k2++) {
                int xi = x0 + dxs[k2], yi = y0 + dys[k2];
                bool ok = (xi >= 0) && (xi < 50) && (yi >= 0) && (yi < 28);
                s_cw[d][k2]  = ok ? cw[k2] * wgt : 0.f;
                s_idx[d][k2] = ok ? (yi * 50 + xi) * 256 : 0;
            }
        }
        __syncthreads();
        const float* vb = vals + (long)c * 358400 + d;
        for (int pt = 0; pt < 32; pt++) {
            #pragma unroll
            for (int k2 = 0; k2 < 4; k2++) {
                float cwv = s_cw[pt][k2];
                if (cwv != 0.f) acc += cwv * vb[s_idx[pt][k2]];
            }
        }
    }
    out[(long)q * 256 + d] = acc;
}

// =====================================================================================
extern "C" void kernel_launch(void* const* d_in, const int* in_sizes, int n_in,
                              void* d_out, int out_size, void* d_ws, size_t ws_size,
                              hipStream_t stream)
{
    const float* images = (const float*)d_in[0];
    const float* intr   = (const float*)d_in[1];
    const float* e2c    = (const float*)d_in[2];
    const float* bevq   = (const float*)d_in[3];
    const float* bevp   = (const float*)d_in[4];
    const float* bbw[5]    = {(const float*)d_in[5],  (const float*)d_in[9],  (const float*)d_in[13], (const float*)d_in[17], (const float*)d_in[21]};
    const float* bbb[5]    = {(const float*)d_in[6],  (const float*)d_in[10], (const float*)d_in[14], (const float*)d_in[18], (const float*)d_in[22]};
    const float* bbg[5]    = {(const float*)d_in[7],  (const float*)d_in[11], (const float*)d_in[15], (const float*)d_in[19], (const float*)d_in[23]};
    const float* bbbeta[5] = {(const float*)d_in[8],  (const float*)d_in[12], (const float*)d_in[16], (const float*)d_in[20], (const float*)d_in[24]};
    const float* sa_wq = (const float*)d_in[25]; const float* sa_bq = (const float*)d_in[26];
    const float* sa_wk = (const float*)d_in[27]; const float* sa_bk = (const float*)d_in[28];
    const float* sa_wv = (const float*)d_in[29]; const float* sa_bv = (const float*)d_in[30];
    const float* sa_wo = (const float*)d_in[31]; const float* sa_bo = (const float*)d_in[32];
    const float* ln1g = (const float*)d_in[33]; const float* ln1b = (const float*)d_in[34];
    const float* ln2g = (const float*)d_in[35]; const float* ln2b = (const float*)d_in[36];
    const float* ln3g = (const float*)d_in[37]; const float* ln3b = (const float*)d_in[38];
    const float* offw = (const float*)d_in[39]; const float* offb = (const float*)d_in[40];
    const float* wtw  = (const float*)d_in[41]; const float* wtb  = (const float*)d_in[42];
    const float* valw = (const float*)d_in[43]; const float* valb = (const float*)d_in[44];
    const float* outw = (const float*)d_in[45]; const float* outb = (const float*)d_in[46];
    const float* fw1  = (const float*)d_in[47]; const float* fb1  = (const float*)d_in[48];
    const float* fw2  = (const float*)d_in[49]; const float* fb2  = (const float*)d_in[50];

    float* ws = (float*)d_ws;
    float* bbA   = ws;            ws += 5734400;   // conv0 out (64,224,400) per cam
    float* bbB   = ws;            ws += 2867200;   // conv1 out (128,112,200) per cam
    float* feats = ws;            ws += 2150400;   // (6,1400,256) hwd
    float* valsb = ws;            ws += 2150400;   // (6,1400,256) hwd
    float* qbuf  = ws;            ws += 640000;
    float* xq    = ws;            ws += 640000;
    float* bQ    = ws;            ws += 640000;
    float* bK    = ws;            ws += 640000;
    float* bV    = ws;            ws += 640000;
    float* bO    = ws;            ws += 640000;
    float* bH    = ws;            ws += 2560000;   // ffn hidden / offsets
    float* bW    = ws;            ws += 480000;    // logits/weights (2500,192)
    float* refp  = ws;            ws += 30016;
    int*   validb = (int*)ws;     ws += 15040;
    float* stats = ws;            ws += 64;

    auto gemm = [&](const float* A, long ars, long aks, const float* B, long bks, long bns,
                    const float* bias, const float* resid, float* C, int M, int N, int K, int act) {
        dim3 g(N / 64, (M + 63) / 64);
        gemm_k<<<g, 256, 0, stream>>>(A, ars, aks, B, bks, bns, bias, resid, C, M, N, K, act);
    };

    // ---- projection of BEV grid ----
    project_k<<<(15000 + 255) / 256, 256, 0, stream>>>(intr, e2c, refp, validb);

    // ---- backbone, per camera ----
    for (int c = 0; c < 6; c++) {
        const float* img = images + (long)c * 3 * 448 * 800;
        conv3x3_s2_k<<<(5734400 + 255) / 256, 256, 0, stream>>>(img, bbw[0], bbb[0], bbA, 3, 64, 448, 800);
        gn_stats_k<<<32, 256, 0, stream>>>(bbA, (long)2 * 224 * 400, stats);
        gn_apply_k<<<(5734400 + 255) / 256, 256, 0, stream>>>(bbA, bbg[0], bbbeta[0], stats, 224 * 400, 2, 5734400, 1);

        conv3x3_s2_k<<<(2867200 + 255) / 256, 256, 0, stream>>>(bbA, bbw[1], bbb[1], bbB, 64, 128, 224, 400);
        gn_stats_k<<<32, 256, 0, stream>>>(bbB, (long)4 * 112 * 200, stats);
        gn_apply_k<<<(2867200 + 255) / 256, 256, 0, stream>>>(bbB, bbg[1], bbbeta[1], stats, 112 * 200, 4, 2867200, 1);

        conv3x3_s2_k<<<(1433600 + 255) / 256, 256, 0, stream>>>(bbB, bbw[2], bbb[2], bbA, 128, 256, 112, 200);
        gn_stats_k<<<32, 256, 0, stream>>>(bbA, (long)8 * 56 * 100, stats);
        gn_apply_k<<<(1433600 + 255) / 256, 256, 0, stream>>>(bbA, bbg[2], bbbeta[2], stats, 56 * 100, 8, 1433600, 1);

        conv3x3_s2_k<<<(358400 + 255) / 256, 256, 0, stream>>>(bbA, bbw[3], bbb[3], bbB, 256, 256, 56, 100);
        gn_stats_k<<<32, 256, 0, stream>>>(bbB, (long)8 * 28 * 50, stats);
        gn_apply_k<<<(358400 + 255) / 256, 256, 0, stream>>>(bbB, bbg[3], bbbeta[3], stats, 28 * 50, 8, 358400, 1);

        // conv4 1x1 as GEMM: rows=p (a_rs=1, a_ks=1400), B = w4[co][ci] -> b_ks=1, b_ns=256
        gemm(bbB, 1, 1400, bbw[4], 1, 256, bbb[4], nullptr, feats + (long)c * 358400, 1400, 256, 256, 0);
        gn_stats_hwd_k<<<32, 256, 0, stream>>>(feats + (long)c * 358400, stats);
        gn_apply_hwd_k<<<1400, 256, 0, stream>>>(feats + (long)c * 358400, bbg[4], bbbeta[4], stats);
    }

    // ---- transformer ----
    qinit_k<<<2500, 256, 0, stream>>>(bevq, bevp, qbuf);

    for (int l = 0; l < 2; l++) {
        long o2 = (long)l * 65536, o1 = (long)l * 256;

        // self-attention
        ln_k<<<625, 256, 0, stream>>>(qbuf, ln1g + o1, ln1b + o1, xq);
        gemm(xq, 256, 1, sa_wq + o2, 256, 1, sa_bq + o1, nullptr, bQ, 2500, 256, 256, 0);
        gemm(xq, 256, 1, sa_wk + o2, 256, 1, sa_bk + o1, nullptr, bK, 2500, 256, 256, 0);
        gemm(xq, 256, 1, sa_wv + o2, 256, 1, sa_bv + o1, nullptr, bV, 2500, 256, 256, 0);
        flash_k<<<dim3(2500, 8), 64, 0, stream>>>(bQ, bK, bV, bO);
        gemm(bO, 256, 1, sa_wo + o2, 256, 1, sa_bo + o1, qbuf, qbuf, 2500, 256, 256, 0);

        // spatial cross-attention
        ln_k<<<625, 256, 0, stream>>>(qbuf, ln2g + o1, ln2b + o1, xq);
        gemm(feats, 256, 1, valw + o2, 256, 1, valb + o1, nullptr, valsb, 8400, 256, 256, 0);
        gemm(xq, 256, 1, offw + (long)l * 256 * 384, 384, 1, offb + (long)l * 384, nullptr, bH, 2500, 384, 256, 0);
        gemm(xq, 256, 1, wtw + (long)l * 256 * 192, 192, 1, wtb + (long)l * 192, nullptr, bW, 2500, 192, 256, 0);
        scasoftmax_k<<<2500, 64, 0, stream>>>(bW, validb);
        sample_k<<<2500, 256, 0, stream>>>(valsb, bH, bW, refp, validb, bO);
        gemm(bO, 256, 1, outw + o2, 256, 1, outb + o1, qbuf, qbuf, 2500, 256, 256, 0);

        // FFN
        ln_k<<<625, 256, 0, stream>>>(qbuf, ln3g + o1, ln3b + o1, xq);
        gemm(xq, 256, 1, fw1 + (long)l * 262144, 1024, 1, fb1 + (long)l * 1024, nullptr, bH, 2500, 1024, 256, 2);
        // final layer's FFN-2 writes directly to d_out (residual from qbuf)
        gemm(bH, 1024, 1, fw2 + (long)l * 262144, 256, 1, fb2 + o1, qbuf,
             (l == 1) ? (float*)d_out : qbuf, 2500, 256, 1024, 0);
    }
}

// Round 3
// 10974.904 us; speedup vs baseline: 2.0693x; 2.0693x over previous
//
#include <hip/hip_runtime.h>
#include <hip/hip_bf16.h>
#include <math.h>

#define EPS 1e-5f

// ---------------- conv 3x3 stride-2 pad-1 as implicit GEMM ----------------
// C[m=cout][n=spatial] = sum_k W[cout][k] * im2col[k][n],  k = ci*9+kh*3+kw
__global__ __launch_bounds__(256) void conv_gemm_k(const float* __restrict__ in,   // (Cin,Hin,Win)
                                                   const float* __restrict__ w,    // (Cout, Cin*9)
                                                   const float* __restrict__ bias,
                                                   float* __restrict__ out,        // (Cout,Hout,Wout)
                                                   int Cin, int Cout, int Hin, int Win)
{
    const int Hout = Hin >> 1, Wout = Win >> 1;
    const int HWo = Hout * Wout;
    const int Ktot = Cin * 9;
    __shared__ float As[16][68];   // [k][m] weights
    __shared__ float Bs[16][68];   // [k][n] im2col
    int tid = threadIdx.x;
    int tx = tid & 15, ty = tid >> 4;
    int m0 = blockIdx.y * 64;      // Cout tile
    int n0 = blockIdx.x * 64;      // spatial tile
    // B-load mapping: this thread fills Bs[kb][nb..nb+3]
    int kb = tid >> 4;
    int nb = (tid & 15) * 4;
    // A-load mapping: fills As[ka0..ka0+3][ma]
    int ma = tid >> 2;
    int ka0 = (tid & 3) * 4;
    // per-thread spatial precompute for the 4 B columns
    int hibase[4], wibase[4], pmask[4];
    #pragma unroll
    for (int u = 0; u < 4; u++) {
        int p = n0 + nb + u;
        pmask[u] = p < HWo;
        int pc = pmask[u] ? p : (HWo - 1);
        int ho = pc / Wout, wo = pc - ho * Wout;
        hibase[u] = ho * 2 - 1;
        wibase[u] = wo * 2 - 1;
    }
    float acc[4][4] = {{0.f}};
    const long wrow = (long)(m0 + ma) * Ktot;
    for (int kt = 0; kt < Ktot; kt += 16) {
        // stage A (weights)
        #pragma unroll
        for (int u = 0; u < 4; u++) {
            int k = kt + ka0 + u;
            As[ka0 + u][ma] = (k < Ktot) ? w[wrow + k] : 0.f;
        }
        // stage B (gathered input)
        int k = kt + kb;
        float bvals[4] = {0.f, 0.f, 0.f, 0.f};
        if (k < Ktot) {
            int ci = k / 9, r = k - ci * 9;
            int kh = r / 3, kw = r - kh * 3;
            const float* ip = in + (long)ci * Hin * Win;
            #pragma unroll
            for (int u = 0; u < 4; u++) {
                int hi = hibase[u] + kh;
                int wi = wibase[u] + kw;
                if (pmask[u] && hi >= 0 && hi < Hin && wi >= 0 && wi < Win)
                    bvals[u] = ip[(long)hi * Win + wi];
            }
        }
        #pragma unroll
        for (int u = 0; u < 4; u++) Bs[kb][nb + u] = bvals[u];
        __syncthreads();
        #pragma unroll
        for (int kk = 0; kk < 16; kk++) {
            float av[4], bv[4];
            #pragma unroll
            for (int i = 0; i < 4; i++) av[i] = As[kk][ty * 4 + i];
            #pragma unroll
            for (int j = 0; j < 4; j++) bv[j] = Bs[kk][tx * 4 + j];
            #pragma unroll
            for (int i = 0; i < 4; i++)
                #pragma unroll
                for (int j = 0; j < 4; j++)
                    acc[i][j] += av[i] * bv[j];
        }
        __syncthreads();
    }
    #pragma unroll
    for (int i = 0; i < 4; i++) {
        int m = m0 + ty * 4 + i;
        float bb = bias[m];
        #pragma unroll
        for (int j = 0; j < 4; j++) {
            int n = n0 + tx * 4 + j;
            if (n < HWo) out[(long)m * HWo + n] = acc[i][j] + bb;
        }
    }
}

// ---------------- GroupNorm (CHW layout, channels contiguous per group) ----------------
__global__ __launch_bounds__(256) void gn_stats_k(const float* __restrict__ x, long grpLen,
                                                  float* __restrict__ stats)
{
    int g = blockIdx.x;
    const float* p = x + (long)g * grpLen;
    float s = 0.f, s2 = 0.f;
    for (long i = threadIdx.x; i < grpLen; i += blockDim.x) {
        float v = p[i];
        s += v; s2 += v * v;
    }
    __shared__ float rs[256], rq[256];
    rs[threadIdx.x] = s; rq[threadIdx.x] = s2;
    __syncthreads();
    for (int o = 128; o > 0; o >>= 1) {
        if (threadIdx.x < o) { rs[threadIdx.x] += rs[threadIdx.x + o]; rq[threadIdx.x] += rq[threadIdx.x + o]; }
        __syncthreads();
    }
    if (threadIdx.x == 0) {
        float mean = rs[0] / (float)grpLen;
        float var  = rq[0] / (float)grpLen - mean * mean;
        stats[g * 2]     = mean;
        stats[g * 2 + 1] = rsqrtf(var + EPS);
    }
}

__global__ __launch_bounds__(256) void gn_apply_k(float* __restrict__ x,
                                                  const float* __restrict__ gamma,
                                                  const float* __restrict__ beta,
                                                  const float* __restrict__ stats,
                                                  int HW, int cpg, int total, int relu)
{
    int idx = blockIdx.x * blockDim.x + threadIdx.x;
    if (idx >= total) return;
    int c = idx / HW;
    int g = c / cpg;
    float v = (x[idx] - stats[g * 2]) * stats[g * 2 + 1] * gamma[c] + beta[c];
    if (relu) v = fmaxf(v, 0.f);
    x[idx] = v;
}

// ---------------- GroupNorm for feats in HWD layout (1400 x 256 per cam, cpg=8) ----------------
__global__ __launch_bounds__(256) void gn_stats_hwd_k(const float* __restrict__ x, float* __restrict__ stats)
{
    int g = blockIdx.x;  // 32 groups
    float s = 0.f, s2 = 0.f;
    for (int i = threadIdx.x; i < 1400 * 8; i += blockDim.x) {
        int p = i >> 3, c = g * 8 + (i & 7);
        float v = x[(long)p * 256 + c];
        s += v; s2 += v * v;
    }
    __shared__ float rs[256], rq[256];
    rs[threadIdx.x] = s; rq[threadIdx.x] = s2;
    __syncthreads();
    for (int o = 128; o > 0; o >>= 1) {
        if (threadIdx.x < o) { rs[threadIdx.x] += rs[threadIdx.x + o]; rq[threadIdx.x] += rq[threadIdx.x + o]; }
        __syncthreads();
    }
    if (threadIdx.x == 0) {
        float mean = rs[0] / 11200.f;
        float var  = rq[0] / 11200.f - mean * mean;
        stats[g * 2]     = mean;
        stats[g * 2 + 1] = rsqrtf(var + EPS);
    }
}

__global__ __launch_bounds__(256) void gn_apply_hwd_k(float* __restrict__ x,
                                                      const float* __restrict__ gamma,
                                                      const float* __restrict__ beta,
                                                      const float* __restrict__ stats)
{
    int idx = blockIdx.x * blockDim.x + threadIdx.x;  // 1400*256
    if (idx >= 1400 * 256) return;
    int c = idx & 255;
    int g = c >> 3;
    x[idx] = (x[idx] - stats[g * 2]) * stats[g * 2 + 1] * gamma[c] + beta[c];
}

// ---------------- generic tiled GEMM: C[M,N] = A(MxK, strided) @ B(KxN, strided) ----------------
__global__ __launch_bounds__(256) void gemm_k(const float* __restrict__ A, long a_rs, long a_ks,
                                              const float* __restrict__ B, long b_ks, long b_ns,
                                              const float* __restrict__ bias,
                                              const float* __restrict__ resid,
                                              float* __restrict__ C,
                                              int M, int N, int K, int act)
{
    __shared__ float As[16][68];
    __shared__ float Bs[16][68];
    int tid = threadIdx.x;
    int tx = tid & 15, ty = tid >> 4;
    int m0 = blockIdx.y * 64, n0 = blockIdx.x * 64;
    float acc[4][4] = {{0.f}};
    for (int kt = 0; kt < K; kt += 16) {
        #pragma unroll
        for (int u = 0; u < 4; u++) {
            int e  = tid * 4 + u;          // 0..1023
            int ka = e & 15, mm = e >> 4;  // A: 64 rows x 16 k
            int gm = m0 + mm;
            As[ka][mm] = (gm < M) ? A[(long)gm * a_rs + (long)(kt + ka) * a_ks] : 0.f;
            int nn = e & 63, kb = e >> 6;  // B: 16 k x 64 cols
            Bs[kb][nn] = B[(long)(kt + kb) * b_ks + (long)(n0 + nn) * b_ns];
        }
        __syncthreads();
        #pragma unroll
        for (int kk = 0; kk < 16; kk++) {
            float av[4], bv[4];
            #pragma unroll
            for (int i = 0; i < 4; i++) av[i] = As[kk][ty * 4 + i];
            #pragma unroll
            for (int j = 0; j < 4; j++) bv[j] = Bs[kk][tx * 4 + j];
            #pragma unroll
            for (int i = 0; i < 4; i++)
                #pragma unroll
                for (int j = 0; j < 4; j++)
                    acc[i][j] += av[i] * bv[j];
        }
        __syncthreads();
    }
    #pragma unroll
    for (int i = 0; i < 4; i++) {
        int r = m0 + ty * 4 + i;
        if (r >= M) continue;
        #pragma unroll
        for (int j = 0; j < 4; j++) {
            int cn = n0 + tx * 4 + j;
            float v = acc[i][j];
            if (bias) v += bias[cn];
            if (act == 2) v = 0.5f * v * (1.f + erff(v * 0.70710678118654752f));
            if (resid) v += resid[(long)r * N + cn];
            C[(long)r * N + cn] = v;
        }
    }
}

// ---------------- 64x64 LDS tile transpose: in (R x C) -> out (C x R) ----------------
__global__ __launch_bounds__(256) void transpose_k(const float* __restrict__ in, float* __restrict__ out,
                                                   int R, int C)
{
    __shared__ float t[64][65];
    int r0 = blockIdx.y * 64, c0 = blockIdx.x * 64;
    int tid = threadIdx.x;
    int cl = tid & 63, rq = tid >> 6;
    #pragma unroll
    for (int i = 0; i < 16; i++) {
        int rl = rq + i * 4;
        int r = r0 + rl, c = c0 + cl;
        t[rl][cl] = (r < R && c < C) ? in[(long)r * C + c] : 0.f;
    }
    __syncthreads();
    int rl2 = tid & 63, cq = tid >> 6;
    #pragma unroll
    for (int i = 0; i < 16; i++) {
        int cl2 = cq + i * 4;
        int r = r0 + rl2, c = c0 + cl2;
        if (r < R && c < C) out[(long)c * R + r] = t[rl2][cl2];
    }
}

// ---------------- projection of BEV grid into cameras ----------------
__global__ __launch_bounds__(256) void project_k(const float* __restrict__ Kin,
                                                 const float* __restrict__ Ein,
                                                 float* __restrict__ refp, int* __restrict__ valid)
{
    int idx = blockIdx.x * blockDim.x + threadIdx.x;
    if (idx >= 2500 * 6) return;
    int c = idx % 6, q = idx / 6;
    int i = q / 50, j = q % 50;
    float px = (i - 24.5f) * 0.5f;
    float py = (j - 24.5f) * 0.5f;
    const float* E = Ein + c * 16;
    float pc[4];
    #pragma unroll
    for (int r = 0; r < 4; r++)
        pc[r] = E[r * 4 + 0] * px + E[r * 4 + 1] * py + E[r * 4 + 3];
    const float* Km = Kin + c * 9;
    float pix[3];
    #pragma unroll
    for (int r = 0; r < 3; r++)
        pix[r] = Km[r * 3 + 0] * pc[0] + Km[r * 3 + 1] * pc[1] + Km[r * 3 + 2] * pc[2];
    float z = fmaxf(pix[2], 1e-5f);
    float u = pix[0] / z, v = pix[1] / z;
    int ok = (pc[2] > 0.f) && (u >= 0.f) && (u < 800.f) && (v >= 0.f) && (v < 448.f);
    refp[(long)idx * 2 + 0] = 2.f * u / 799.f - 1.f;
    refp[(long)idx * 2 + 1] = 2.f * v / 447.f - 1.f;
    valid[idx] = ok;
}

// ---------------- misc elementwise ----------------
__global__ __launch_bounds__(256) void qinit_k(const float* __restrict__ a, const float* __restrict__ b,
                                               float* __restrict__ y)
{
    int i = blockIdx.x * blockDim.x + threadIdx.x;
    if (i >= 2500 * 256) return;
    y[i] = a[i] + b[i];
}

// ---------------- LayerNorm: one wave per row of 256 ----------------
__global__ __launch_bounds__(256) void ln_k(const float* __restrict__ x,
                                            const float* __restrict__ g, const float* __restrict__ b,
                                            float* __restrict__ y)
{
    int row  = blockIdx.x * 4 + (threadIdx.x >> 6);
    int lane = threadIdx.x & 63;
    if (row >= 2500) return;
    const float* xp = x + (long)row * 256;
    float v[4];
    #pragma unroll
    for (int i = 0; i < 4; i++) v[i] = xp[lane + 64 * i];
    float s  = v[0] + v[1] + v[2] + v[3];
    float s2 = v[0] * v[0] + v[1] * v[1] + v[2] * v[2] + v[3] * v[3];
    #pragma unroll
    for (int o = 32; o > 0; o >>= 1) { s += __shfl_xor(s, o, 64); s2 += __shfl_xor(s2, o, 64); }
    float mean = s * (1.f / 256.f);
    float var  = s2 * (1.f / 256.f) - mean * mean;
    float rstd = rsqrtf(var + EPS);
    #pragma unroll
    for (int i = 0; i < 4; i++) {
        int cc = lane + 64 * i;
        y[(long)row * 256 + cc] = (v[i] - mean) * rstd * g[cc] + b[cc];
    }
}

// ---------------- flash-style MHA: wave per (query, head); K,V transposed (256 x 2500) ----------------
__global__ __launch_bounds__(64) void flash_k(const float* __restrict__ Q,
                                              const float* __restrict__ Kt,   // (256,2500)
                                              const float* __restrict__ Vt,   // (256,2500)
                                              float* __restrict__ O)
{
    int q = blockIdx.x, h = blockIdx.y, lane = threadIdx.x;
    const float scale = 0.17677669529663687f;  // 1/sqrt(32)
    float qv[32];
    const float* qp = Q + (long)q * 256 + h * 32;
    #pragma unroll
    for (int d = 0; d < 32; d++) qv[d] = qp[d] * scale;
    const float* kbase = Kt + (long)h * 32 * 2500;
    const float* vbase = Vt + (long)h * 32 * 2500;
    float m = -INFINITY, lsum = 0.f;
    float oacc[32];
    #pragma unroll
    for (int d = 0; d < 32; d++) oacc[d] = 0.f;
    for (int base = 0; base < 2500; base += 64) {
        int j = base + lane;
        bool act = j < 2500;
        int jj = act ? j : 2499;
        float a = 0.f;
        #pragma unroll
        for (int d = 0; d < 32; d++) a += qv[d] * kbase[d * 2500 + jj];
        float s = act ? a : -INFINITY;
        float cm = s;
        #pragma unroll
        for (int o = 32; o > 0; o >>= 1) cm = fmaxf(cm, __shfl_xor(cm, o, 64));
        float mn = fmaxf(m, cm);
        float alpha = expf(m - mn);  // m=-inf initially -> 0
        float p = act ? expf(s - mn) : 0.f;
        lsum = lsum * alpha + p;
        #pragma unroll
        for (int d = 0; d < 32; d++) oacc[d] = oacc[d] * alpha + p * vbase[d * 2500 + jj];
        m = mn;
    }
    #pragma unroll
    for (int o = 32; o > 0; o >>= 1) lsum += __shfl_xor(lsum, o, 64);
    __shared__ float red[64][33];
    #pragma unroll
    for (int d = 0; d < 32; d++) red[lane][d] = oacc[d];
    __syncthreads();
    if (lane < 32) {
        float tot = 0.f;
        for (int jj2 = 0; jj2 < 64; jj2++) tot += red[jj2][lane];
        O[(long)q * 256 + h * 32 + lane] = tot / lsum;
    }
}

// ---------------- masked softmax over 192 deformable-attn logits per query ----------------
__global__ __launch_bounds__(64) void scasoftmax_k(float* __restrict__ logits, const int* __restrict__ valid)
{
    int q = blockIdx.x, lane = threadIdx.x;
    float v[3]; int mk[3];
    #pragma unroll
    for (int i = 0; i < 3; i++) {
        int idx = i * 64 + lane;
        int c = idx >> 5;
        mk[i] = valid[q * 6 + c];
        v[i] = mk[i] ? logits[(long)q * 192 + idx] : -1e30f;
    }
    float mx = fmaxf(fmaxf(v[0], v[1]), v[2]);
    #pragma unroll
    for (int o = 32; o > 0; o >>= 1) mx = fmaxf(mx, __shfl_xor(mx, o, 64));
    float e[3]; float s = 0.f;
    #pragma unroll
    for (int i = 0; i < 3; i++) { e[i] = expf(v[i] - mx); s += e[i]; }
    #pragma unroll
    for (int o = 32; o > 0; o >>= 1) s += __shfl_xor(s, o, 64);
    float inv = 1.f / s;
    #pragma unroll
    for (int i = 0; i < 3; i++)
        logits[(long)q * 192 + i * 64 + lane] = mk[i] ? e[i] * inv : 0.f;
}

// ---------------- deformable sampling: block per query, thread per channel ----------------
__global__ __launch_bounds__(256) void sample_k(const float* __restrict__ vals,  // (6,1400,256) hwd
                                                const float* __restrict__ offs,  // (2500,384)
                                                const float* __restrict__ wts,   // (2500,192)
                                                const float* __restrict__ refp,  // (2500,6,2)
                                                const int* __restrict__ valid,   // (2500,6)
                                                float* __restrict__ out)         // (2500,256)
{
    int q = blockIdx.x, d = threadIdx.x;
    __shared__ float s_cw[32][4];
    __shared__ int   s_idx[32][4];
    float acc = 0.f;
    for (int c = 0; c < 6; c++) {
        if (!valid[q * 6 + c]) continue;  // block-uniform branch
        __syncthreads();
        if (d < 32) {
            float ox = offs[(long)q * 384 + (c * 32 + d) * 2 + 0];
            float oy = offs[(long)q * 384 + (c * 32 + d) * 2 + 1];
            float px = refp[(q * 6 + c) * 2 + 0] + ox * (2.f / 49.f);
            float py = refp[(q * 6 + c) * 2 + 1] + oy * (2.f / 27.f);
            float gx = (px + 1.f) * 0.5f * 49.f;
            float gy = (py + 1.f) * 0.5f * 27.f;
            float x0f = floorf(gx), y0f = floorf(gy);
            float wx = gx - x0f, wy = gy - y0f;
            int x0 = (int)x0f, y0 = (int)y0f;
            float wgt = wts[(long)q * 192 + c * 32 + d];
            float cw[4] = {(1.f - wx) * (1.f - wy), wx * (1.f - wy), (1.f - wx) * wy, wx * wy};
            const int dxs[4] = {0, 1, 0, 1};
            const int dys[4] = {0, 0, 1, 1};
            #pragma unroll
            for (int k2 = 0; k2 < 4; k2++) {
                int xi = x0 + dxs[k2], yi = y0 + dys[k2];
                bool ok = (xi >= 0) && (xi < 50) && (yi >= 0) && (yi < 28);
                s_cw[d][k2]  = ok ? cw[k2] * wgt : 0.f;
                s_idx[d][k2] = ok ? (yi * 50 + xi) * 256 : 0;
            }
        }
        __syncthreads();
        const float* vb = vals + (long)c * 358400 + d;
        for (int pt = 0; pt < 32; pt++) {
            #pragma unroll
            for (int k2 = 0; k2 < 4; k2++) {
                float cwv = s_cw[pt][k2];
                if (cwv != 0.f) acc += cwv * vb[s_idx[pt][k2]];
            }
        }
    }
    out[(long)q * 256 + d] = acc;
}

// =====================================================================================
extern "C" void kernel_launch(void* const* d_in, const int* in_sizes, int n_in,
                              void* d_out, int out_size, void* d_ws, size_t ws_size,
                              hipStream_t stream)
{
    const float* images = (const float*)d_in[0];
    const float* intr   = (const float*)d_in[1];
    const float* e2c    = (const float*)d_in[2];
    const float* bevq   = (const float*)d_in[3];
    const float* bevp   = (const float*)d_in[4];
    const float* bbw[5]    = {(const float*)d_in[5],  (const float*)d_in[9],  (const float*)d_in[13], (const float*)d_in[17], (const float*)d_in[21]};
    const float* bbb[5]    = {(const float*)d_in[6],  (const float*)d_in[10], (const float*)d_in[14], (const float*)d_in[18], (const float*)d_in[22]};
    const float* bbg[5]    = {(const float*)d_in[7],  (const float*)d_in[11], (const float*)d_in[15], (const float*)d_in[19], (const float*)d_in[23]};
    const float* bbbeta[5] = {(const float*)d_in[8],  (const float*)d_in[12], (const float*)d_in[16], (const float*)d_in[20], (const float*)d_in[24]};
    const float* sa_wq = (const float*)d_in[25]; const float* sa_bq = (const float*)d_in[26];
    const float* sa_wk = (const float*)d_in[27]; const float* sa_bk = (const float*)d_in[28];
    const float* sa_wv = (const float*)d_in[29]; const float* sa_bv = (const float*)d_in[30];
    const float* sa_wo = (const float*)d_in[31]; const float* sa_bo = (const float*)d_in[32];
    const float* ln1g = (const float*)d_in[33]; const float* ln1b = (const float*)d_in[34];
    const float* ln2g = (const float*)d_in[35]; const float* ln2b = (const float*)d_in[36];
    const float* ln3g = (const float*)d_in[37]; const float* ln3b = (const float*)d_in[38];
    const float* offw = (const float*)d_in[39]; const float* offb = (const float*)d_in[40];
    const float* wtw  = (const float*)d_in[41]; const float* wtb  = (const float*)d_in[42];
    const float* valw = (const float*)d_in[43]; const float* valb = (const float*)d_in[44];
    const float* outw = (const float*)d_in[45]; const float* outb = (const float*)d_in[46];
    const float* fw1  = (const float*)d_in[47]; const float* fb1  = (const float*)d_in[48];
    const float* fw2  = (const float*)d_in[49]; const float* fb2  = (const float*)d_in[50];

    float* ws = (float*)d_ws;
    float* bbA   = ws;            ws += 5734400;   // conv0 out (64,224,400) per cam
    float* bbB   = ws;            ws += 2867200;   // conv1 out (128,112,200) per cam
    float* feats = ws;            ws += 2150400;   // (6,1400,256) hwd
    float* valsb = ws;            ws += 2150400;   // (6,1400,256) hwd
    float* qbuf  = ws;            ws += 640000;
    float* xq    = ws;            ws += 640000;
    float* bQ    = ws;            ws += 640000;
    float* bK    = ws;            ws += 640000;
    float* bV    = ws;            ws += 640000;
    float* bO    = ws;            ws += 640000;
    float* bH    = ws;            ws += 2560000;   // ffn hidden / offsets / K^T,V^T scratch
    float* bW    = ws;            ws += 480000;    // logits/weights (2500,192)
    float* refp  = ws;            ws += 30016;
    int*   validb = (int*)ws;     ws += 15040;
    float* stats = ws;            ws += 64;
    float* bKt = bH;              // (256,2500) — bH is free during self-attention
    float* bVt = bH + 640000;

    auto gemm = [&](const float* A, long ars, long aks, const float* B, long bks, long bns,
                    const float* bias, const float* resid, float* C, int M, int N, int K, int act) {
        dim3 g(N / 64, (M + 63) / 64);
        gemm_k<<<g, 256, 0, stream>>>(A, ars, aks, B, bks, bns, bias, resid, C, M, N, K, act);
    };
    auto conv = [&](const float* in, const float* w, const float* bias, float* out,
                    int Cin, int Cout, int Hin, int Win) {
        int HWo = (Hin >> 1) * (Win >> 1);
        dim3 g((HWo + 63) / 64, Cout / 64);
        conv_gemm_k<<<g, 256, 0, stream>>>(in, w, bias, out, Cin, Cout, Hin, Win);
    };

    // ---- projection of BEV grid ----
    project_k<<<(15000 + 255) / 256, 256, 0, stream>>>(intr, e2c, refp, validb);

    // ---- backbone, per camera ----
    for (int c = 0; c < 6; c++) {
        const float* img = images + (long)c * 3 * 448 * 800;
        conv(img, bbw[0], bbb[0], bbA, 3, 64, 448, 800);
        gn_stats_k<<<32, 256, 0, stream>>>(bbA, (long)2 * 224 * 400, stats);
        gn_apply_k<<<(5734400 + 255) / 256, 256, 0, stream>>>(bbA, bbg[0], bbbeta[0], stats, 224 * 400, 2, 5734400, 1);

        conv(bbA, bbw[1], bbb[1], bbB, 64, 128, 224, 400);
        gn_stats_k<<<32, 256, 0, stream>>>(bbB, (long)4 * 112 * 200, stats);
        gn_apply_k<<<(2867200 + 255) / 256, 256, 0, stream>>>(bbB, bbg[1], bbbeta[1], stats, 112 * 200, 4, 2867200, 1);

        conv(bbB, bbw[2], bbb[2], bbA, 128, 256, 112, 200);
        gn_stats_k<<<32, 256, 0, stream>>>(bbA, (long)8 * 56 * 100, stats);
        gn_apply_k<<<(1433600 + 255) / 256, 256, 0, stream>>>(bbA, bbg[2], bbbeta[2], stats, 56 * 100, 8, 1433600, 1);

        conv(bbA, bbw[3], bbb[3], bbB, 256, 256, 56, 100);
        gn_stats_k<<<32, 256, 0, stream>>>(bbB, (long)8 * 28 * 50, stats);
        gn_apply_k<<<(358400 + 255) / 256, 256, 0, stream>>>(bbB, bbg[3], bbbeta[3], stats, 28 * 50, 8, 358400, 1);

        // conv4 1x1 as GEMM: rows=p (a_rs=1, a_ks=1400), B = w4[co][ci] -> b_ks=1, b_ns=256
        gemm(bbB, 1, 1400, bbw[4], 1, 256, bbb[4], nullptr, feats + (long)c * 358400, 1400, 256, 256, 0);
        gn_stats_hwd_k<<<32, 256, 0, stream>>>(feats + (long)c * 358400, stats);
        gn_apply_hwd_k<<<1400, 256, 0, stream>>>(feats + (long)c * 358400, bbg[4], bbbeta[4], stats);
    }

    // ---- transformer ----
    qinit_k<<<2500, 256, 0, stream>>>(bevq, bevp, qbuf);

    for (int l = 0; l < 2; l++) {
        long o2 = (long)l * 65536, o1 = (long)l * 256;

        // self-attention
        ln_k<<<625, 256, 0, stream>>>(qbuf, ln1g + o1, ln1b + o1, xq);
        gemm(xq, 256, 1, sa_wq + o2, 256, 1, sa_bq + o1, nullptr, bQ, 2500, 256, 256, 0);
        gemm(xq, 256, 1, sa_wk + o2, 256, 1, sa_bk + o1, nullptr, bK, 2500, 256, 256, 0);
        gemm(xq, 256, 1, sa_wv + o2, 256, 1, sa_bv + o1, nullptr, bV, 2500, 256, 256, 0);
        transpose_k<<<dim3(4, 40), 256, 0, stream>>>(bK, bKt, 2500, 256);
        transpose_k<<<dim3(4, 40), 256, 0, stream>>>(bV, bVt, 2500, 256);
        flash_k<<<dim3(2500, 8), 64, 0, stream>>>(bQ, bKt, bVt, bO);
        gemm(bO, 256, 1, sa_wo + o2, 256, 1, sa_bo + o1, qbuf, qbuf, 2500, 256, 256, 0);

        // spatial cross-attention
        ln_k<<<625, 256, 0, stream>>>(qbuf, ln2g + o1, ln2b + o1, xq);
        gemm(feats, 256, 1, valw + o2, 256, 1, valb + o1, nullptr, valsb, 8400, 256, 256, 0);
        gemm(xq, 256, 1, offw + (long)l * 256 * 384, 384, 1, offb + (long)l * 384, nullptr, bH, 2500, 384, 256, 0);
        gemm(xq, 256, 1, wtw + (long)l * 256 * 192, 192, 1, wtb + (long)l * 192, nullptr, bW, 2500, 192, 256, 0);
        scasoftmax_k<<<2500, 64, 0, stream>>>(bW, validb);
        sample_k<<<2500, 256, 0, stream>>>(valsb, bH, bW, refp, validb, bO);
        gemm(bO, 256, 1, outw + o2, 256, 1, outb + o1, qbuf, qbuf, 2500, 256, 256, 0);

        // FFN
        ln_k<<<625, 256, 0, stream>>>(qbuf, ln3g + o1, ln3b + o1, xq);
        gemm(xq, 256, 1, fw1 + (long)l * 262144, 1024, 1, fb1 + (long)l * 1024, nullptr, bH, 2500, 1024, 256, 2);
        // final layer's FFN-2 writes directly to d_out (residual from qbuf)
        gemm(bH, 1024, 1, fw2 + (long)l * 262144, 256, 1, fb2 + o1, qbuf,
             (l == 1) ? (float*)d_out : qbuf, 2500, 256, 1024, 0);
    }
}

// Round 4
// 7435.928 us; speedup vs baseline: 3.0541x; 1.4759x over previous
//
#include <hip/hip_runtime.h>
#include <hip/hip_bf16.h>
#include <math.h>

#define EPS 1e-5f
#define FL_SPLITS 5
#define FL_KEYS 500

// ---------------- conv 3x3 stride-2 pad-1 as implicit GEMM ----------------
__global__ __launch_bounds__(256) void conv_gemm_k(const float* __restrict__ in,   // (Cin,Hin,Win)
                                                   const float* __restrict__ w,    // (Cout, Cin*9)
                                                   const float* __restrict__ bias,
                                                   float* __restrict__ out,        // (Cout,Hout,Wout)
                                                   int Cin, int Cout, int Hin, int Win)
{
    const int Hout = Hin >> 1, Wout = Win >> 1;
    const int HWo = Hout * Wout;
    const int Ktot = Cin * 9;
    __shared__ float As[16][68];   // [k][m] weights
    __shared__ float Bs[16][68];   // [k][n] im2col
    int tid = threadIdx.x;
    int tx = tid & 15, ty = tid >> 4;
    int m0 = blockIdx.y * 64;      // Cout tile
    int n0 = blockIdx.x * 64;      // spatial tile
    int kb = tid >> 4;
    int nb = (tid & 15) * 4;
    int ma = tid >> 2;
    int ka0 = (tid & 3) * 4;
    int hibase[4], wibase[4], pmask[4];
    #pragma unroll
    for (int u = 0; u < 4; u++) {
        int p = n0 + nb + u;
        pmask[u] = p < HWo;
        int pc = pmask[u] ? p : (HWo - 1);
        int ho = pc / Wout, wo = pc - ho * Wout;
        hibase[u] = ho * 2 - 1;
        wibase[u] = wo * 2 - 1;
    }
    float acc[4][4] = {{0.f}};
    const long wrow = (long)(m0 + ma) * Ktot;
    for (int kt = 0; kt < Ktot; kt += 16) {
        #pragma unroll
        for (int u = 0; u < 4; u++) {
            int k = kt + ka0 + u;
            As[ka0 + u][ma] = (k < Ktot) ? w[wrow + k] : 0.f;
        }
        int k = kt + kb;
        float bvals[4] = {0.f, 0.f, 0.f, 0.f};
        if (k < Ktot) {
            int ci = k / 9, r = k - ci * 9;
            int kh = r / 3, kw = r - kh * 3;
            const float* ip = in + (long)ci * Hin * Win;
            #pragma unroll
            for (int u = 0; u < 4; u++) {
                int hi = hibase[u] + kh;
                int wi = wibase[u] + kw;
                if (pmask[u] && hi >= 0 && hi < Hin && wi >= 0 && wi < Win)
                    bvals[u] = ip[(long)hi * Win + wi];
            }
        }
        #pragma unroll
        for (int u = 0; u < 4; u++) Bs[kb][nb + u] = bvals[u];
        __syncthreads();
        #pragma unroll
        for (int kk = 0; kk < 16; kk++) {
            float av[4], bv[4];
            #pragma unroll
            for (int i = 0; i < 4; i++) av[i] = As[kk][ty * 4 + i];
            #pragma unroll
            for (int j = 0; j < 4; j++) bv[j] = Bs[kk][tx * 4 + j];
            #pragma unroll
            for (int i = 0; i < 4; i++)
                #pragma unroll
                for (int j = 0; j < 4; j++)
                    acc[i][j] += av[i] * bv[j];
        }
        __syncthreads();
    }
    #pragma unroll
    for (int i = 0; i < 4; i++) {
        int m = m0 + ty * 4 + i;
        float bb = bias[m];
        #pragma unroll
        for (int j = 0; j < 4; j++) {
            int n = n0 + tx * 4 + j;
            if (n < HWo) out[(long)m * HWo + n] = acc[i][j] + bb;
        }
    }
}

// ---------------- GroupNorm (CHW layout) ----------------
__global__ __launch_bounds__(256) void gn_stats_k(const float* __restrict__ x, long grpLen,
                                                  float* __restrict__ stats)
{
    int g = blockIdx.x;
    const float* p = x + (long)g * grpLen;
    float s = 0.f, s2 = 0.f;
    for (long i = threadIdx.x; i < grpLen; i += blockDim.x) {
        float v = p[i];
        s += v; s2 += v * v;
    }
    __shared__ float rs[256], rq[256];
    rs[threadIdx.x] = s; rq[threadIdx.x] = s2;
    __syncthreads();
    for (int o = 128; o > 0; o >>= 1) {
        if (threadIdx.x < o) { rs[threadIdx.x] += rs[threadIdx.x + o]; rq[threadIdx.x] += rq[threadIdx.x + o]; }
        __syncthreads();
    }
    if (threadIdx.x == 0) {
        float mean = rs[0] / (float)grpLen;
        float var  = rq[0] / (float)grpLen - mean * mean;
        stats[g * 2]     = mean;
        stats[g * 2 + 1] = rsqrtf(var + EPS);
    }
}

__global__ __launch_bounds__(256) void gn_apply_k(float* __restrict__ x,
                                                  const float* __restrict__ gamma,
                                                  const float* __restrict__ beta,
                                                  const float* __restrict__ stats,
                                                  int HW, int cpg, int total, int relu)
{
    int idx = blockIdx.x * blockDim.x + threadIdx.x;
    if (idx >= total) return;
    int c = idx / HW;
    int g = c / cpg;
    float v = (x[idx] - stats[g * 2]) * stats[g * 2 + 1] * gamma[c] + beta[c];
    if (relu) v = fmaxf(v, 0.f);
    x[idx] = v;
}

// ---------------- GroupNorm for feats in HWD layout ----------------
__global__ __launch_bounds__(256) void gn_stats_hwd_k(const float* __restrict__ x, float* __restrict__ stats)
{
    int g = blockIdx.x;  // 32 groups
    float s = 0.f, s2 = 0.f;
    for (int i = threadIdx.x; i < 1400 * 8; i += blockDim.x) {
        int p = i >> 3, c = g * 8 + (i & 7);
        float v = x[(long)p * 256 + c];
        s += v; s2 += v * v;
    }
    __shared__ float rs[256], rq[256];
    rs[threadIdx.x] = s; rq[threadIdx.x] = s2;
    __syncthreads();
    for (int o = 128; o > 0; o >>= 1) {
        if (threadIdx.x < o) { rs[threadIdx.x] += rs[threadIdx.x + o]; rq[threadIdx.x] += rq[threadIdx.x + o]; }
        __syncthreads();
    }
    if (threadIdx.x == 0) {
        float mean = rs[0] / 11200.f;
        float var  = rq[0] / 11200.f - mean * mean;
        stats[g * 2]     = mean;
        stats[g * 2 + 1] = rsqrtf(var + EPS);
    }
}

__global__ __launch_bounds__(256) void gn_apply_hwd_k(float* __restrict__ x,
                                                      const float* __restrict__ gamma,
                                                      const float* __restrict__ beta,
                                                      const float* __restrict__ stats)
{
    int idx = blockIdx.x * blockDim.x + threadIdx.x;  // 1400*256
    if (idx >= 1400 * 256) return;
    int c = idx & 255;
    int g = c >> 3;
    x[idx] = (x[idx] - stats[g * 2]) * stats[g * 2 + 1] * gamma[c] + beta[c];
}

// ---------------- generic tiled GEMM ----------------
__global__ __launch_bounds__(256) void gemm_k(const float* __restrict__ A, long a_rs, long a_ks,
                                              const float* __restrict__ B, long b_ks, long b_ns,
                                              const float* __restrict__ bias,
                                              const float* __restrict__ resid,
                                              float* __restrict__ C,
                                              int M, int N, int K, int act)
{
    __shared__ float As[16][68];
    __shared__ float Bs[16][68];
    int tid = threadIdx.x;
    int tx = tid & 15, ty = tid >> 4;
    int m0 = blockIdx.y * 64, n0 = blockIdx.x * 64;
    float acc[4][4] = {{0.f}};
    for (int kt = 0; kt < K; kt += 16) {
        #pragma unroll
        for (int u = 0; u < 4; u++) {
            int e  = tid * 4 + u;
            int ka = e & 15, mm = e >> 4;
            int gm = m0 + mm;
            As[ka][mm] = (gm < M) ? A[(long)gm * a_rs + (long)(kt + ka) * a_ks] : 0.f;
            int nn = e & 63, kb = e >> 6;
            Bs[kb][nn] = B[(long)(kt + kb) * b_ks + (long)(n0 + nn) * b_ns];
        }
        __syncthreads();
        #pragma unroll
        for (int kk = 0; kk < 16; kk++) {
            float av[4], bv[4];
            #pragma unroll
            for (int i = 0; i < 4; i++) av[i] = As[kk][ty * 4 + i];
            #pragma unroll
            for (int j = 0; j < 4; j++) bv[j] = Bs[kk][tx * 4 + j];
            #pragma unroll
            for (int i = 0; i < 4; i++)
                #pragma unroll
                for (int j = 0; j < 4; j++)
                    acc[i][j] += av[i] * bv[j];
        }
        __syncthreads();
    }
    #pragma unroll
    for (int i = 0; i < 4; i++) {
        int r = m0 + ty * 4 + i;
        if (r >= M) continue;
        #pragma unroll
        for (int j = 0; j < 4; j++) {
            int cn = n0 + tx * 4 + j;
            float v = acc[i][j];
            if (bias) v += bias[cn];
            if (act == 2) v = 0.5f * v * (1.f + erff(v * 0.70710678118654752f));
            if (resid) v += resid[(long)r * N + cn];
            C[(long)r * N + cn] = v;
        }
    }
}

// ---------------- projection of BEV grid ----------------
__global__ __launch_bounds__(256) void project_k(const float* __restrict__ Kin,
                                                 const float* __restrict__ Ein,
                                                 float* __restrict__ refp, int* __restrict__ valid)
{
    int idx = blockIdx.x * blockDim.x + threadIdx.x;
    if (idx >= 2500 * 6) return;
    int c = idx % 6, q = idx / 6;
    int i = q / 50, j = q % 50;
    float px = (i - 24.5f) * 0.5f;
    float py = (j - 24.5f) * 0.5f;
    const float* E = Ein + c * 16;
    float pc[4];
    #pragma unroll
    for (int r = 0; r < 4; r++)
        pc[r] = E[r * 4 + 0] * px + E[r * 4 + 1] * py + E[r * 4 + 3];
    const float* Km = Kin + c * 9;
    float pix[3];
    #pragma unroll
    for (int r = 0; r < 3; r++)
        pix[r] = Km[r * 3 + 0] * pc[0] + Km[r * 3 + 1] * pc[1] + Km[r * 3 + 2] * pc[2];
    float z = fmaxf(pix[2], 1e-5f);
    float u = pix[0] / z, v = pix[1] / z;
    int ok = (pc[2] > 0.f) && (u >= 0.f) && (u < 800.f) && (v >= 0.f) && (v < 448.f);
    refp[(long)idx * 2 + 0] = 2.f * u / 799.f - 1.f;
    refp[(long)idx * 2 + 1] = 2.f * v / 447.f - 1.f;
    valid[idx] = ok;
}

// ---------------- misc elementwise ----------------
__global__ __launch_bounds__(256) void qinit_k(const float* __restrict__ a, const float* __restrict__ b,
                                               float* __restrict__ y)
{
    int i = blockIdx.x * blockDim.x + threadIdx.x;
    if (i >= 2500 * 256) return;
    y[i] = a[i] + b[i];
}

// ---------------- LayerNorm ----------------
__global__ __launch_bounds__(256) void ln_k(const float* __restrict__ x,
                                            const float* __restrict__ g, const float* __restrict__ b,
                                            float* __restrict__ y)
{
    int row  = blockIdx.x * 4 + (threadIdx.x >> 6);
    int lane = threadIdx.x & 63;
    if (row >= 2500) return;
    const float* xp = x + (long)row * 256;
    float v[4];
    #pragma unroll
    for (int i = 0; i < 4; i++) v[i] = xp[lane + 64 * i];
    float s  = v[0] + v[1] + v[2] + v[3];
    float s2 = v[0] * v[0] + v[1] * v[1] + v[2] * v[2] + v[3] * v[3];
    #pragma unroll
    for (int o = 32; o > 0; o >>= 1) { s += __shfl_xor(s, o, 64); s2 += __shfl_xor(s2, o, 64); }
    float mean = s * (1.f / 256.f);
    float var  = s2 * (1.f / 256.f) - mean * mean;
    float rstd = rsqrtf(var + EPS);
    #pragma unroll
    for (int i = 0; i < 4; i++) {
        int cc = lane + 64 * i;
        y[(long)row * 256 + cc] = (v[i] - mean) * rstd * g[cc] + b[cc];
    }
}

// ---------------- flash-2 tiled MHA with split-K ----------------
// block: 64 queries x 1 head; grid (40, 8, FL_SPLITS); 256 threads = 16x16
__global__ __launch_bounds__(256) void flash2_k(const float* __restrict__ Q,
                                                const float* __restrict__ K,
                                                const float* __restrict__ V,
                                                float* __restrict__ Opart,   // (S,2500,256)
                                                float* __restrict__ MLpart)  // (S,2500,8,2)
{
    const int h  = blockIdx.y;
    const int q0 = blockIdx.x * 64;
    const int sp = blockIdx.z;
    const int kstart = sp * FL_KEYS, kend = kstart + FL_KEYS;
    const int tid = threadIdx.x;
    const int tx = tid & 15, ty = tid >> 4;
    __shared__ float Qs[32][68];
    __shared__ float Ks[32][68];
    __shared__ float Vs[64][33];
    __shared__ float Ps[64][68];
    const float scale = 0.17677669529663687f;  // 1/sqrt(32)
    // stage Q once (scaled)
    #pragma unroll
    for (int u = 0; u < 8; u++) {
        int e = u * 256 + tid;
        int r = e >> 5, d = e & 31;
        int qi = q0 + r;
        Qs[d][r] = (qi < 2500) ? Q[(long)qi * 256 + h * 32 + d] * scale : 0.f;
    }
    float m[4], l[4], o[4][2];
    #pragma unroll
    for (int i = 0; i < 4; i++) { m[i] = -INFINITY; l[i] = 0.f; o[i][0] = 0.f; o[i][1] = 0.f; }
    for (int kb = kstart; kb < kend; kb += 64) {
        __syncthreads();
        #pragma unroll
        for (int u = 0; u < 8; u++) {
            int e = u * 256 + tid;
            int c = e >> 5, d = e & 31;
            int ki = kb + c;
            bool ok = ki < kend;
            Ks[d][c] = ok ? K[(long)ki * 256 + h * 32 + d] : 0.f;
            Vs[c][d] = ok ? V[(long)ki * 256 + h * 32 + d] : 0.f;
        }
        __syncthreads();
        // S = Q K^T  (64x64), thread holds 4x4
        float s[4][4] = {{0.f}};
        #pragma unroll
        for (int d = 0; d < 32; d++) {
            float av[4], bv[4];
            #pragma unroll
            for (int i = 0; i < 4; i++) av[i] = Qs[d][ty * 4 + i];
            #pragma unroll
            for (int j = 0; j < 4; j++) bv[j] = Ks[d][tx * 4 + j];
            #pragma unroll
            for (int i = 0; i < 4; i++)
                #pragma unroll
                for (int j = 0; j < 4; j++)
                    s[i][j] += av[i] * bv[j];
        }
        // mask tail columns
        #pragma unroll
        for (int j = 0; j < 4; j++) {
            if (kb + tx * 4 + j >= kend) {
                #pragma unroll
                for (int i = 0; i < 4; i++) s[i][j] = -1e30f;
            }
        }
        // online softmax (per row, rows = ty*4+i; reduce across 16 tx lanes)
        float p[4][4];
        #pragma unroll
        for (int i = 0; i < 4; i++) {
            float rm = fmaxf(fmaxf(s[i][0], s[i][1]), fmaxf(s[i][2], s[i][3]));
            #pragma unroll
            for (int off = 1; off < 16; off <<= 1) rm = fmaxf(rm, __shfl_xor(rm, off, 16));
            float mn = fmaxf(m[i], rm);
            float alpha = __expf(m[i] - mn);
            float rs = 0.f;
            #pragma unroll
            for (int j = 0; j < 4; j++) { p[i][j] = __expf(s[i][j] - mn); rs += p[i][j]; }
            #pragma unroll
            for (int off = 1; off < 16; off <<= 1) rs += __shfl_xor(rs, off, 16);
            l[i] = l[i] * alpha + rs;
            o[i][0] *= alpha; o[i][1] *= alpha;
            m[i] = mn;
        }
        // write P tile: Ps[j][r], float4 over r
        #pragma unroll
        for (int j = 0; j < 4; j++) {
            float4 pv = make_float4(p[0][j], p[1][j], p[2][j], p[3][j]);
            *(float4*)&Ps[tx * 4 + j][ty * 4] = pv;
        }
        __syncthreads();
        // O += P V  (64x64 @ 64x32), thread cols = tx*2..tx*2+1
        for (int j = 0; j < 64; j++) {
            float4 av = *(const float4*)&Ps[j][ty * 4];
            float b0 = Vs[j][tx * 2], b1 = Vs[j][tx * 2 + 1];
            o[0][0] += av.x * b0; o[0][1] += av.x * b1;
            o[1][0] += av.y * b0; o[1][1] += av.y * b1;
            o[2][0] += av.z * b0; o[2][1] += av.z * b1;
            o[3][0] += av.w * b0; o[3][1] += av.w * b1;
        }
    }
    // write partials
    #pragma unroll
    for (int i = 0; i < 4; i++) {
        int qi = q0 + ty * 4 + i;
        if (qi < 2500) {
            long ob = ((long)sp * 2500 + qi) * 256 + h * 32 + tx * 2;
            Opart[ob]     = o[i][0];
            Opart[ob + 1] = o[i][1];
            if (tx == 0) {
                long mb = (((long)sp * 2500 + qi) * 8 + h) * 2;
                MLpart[mb]     = m[i];
                MLpart[mb + 1] = l[i];
            }
        }
    }
}

__global__ __launch_bounds__(256) void flashmerge_k(const float* __restrict__ Opart,
                                                    const float* __restrict__ MLpart,
                                                    float* __restrict__ O)
{
    int q = blockIdx.x, d = threadIdx.x;
    int h = d >> 5;
    float ms[FL_SPLITS], ls[FL_SPLITS];
    float mg = -INFINITY;
    #pragma unroll
    for (int s = 0; s < FL_SPLITS; s++) {
        long mb = (((long)s * 2500 + q) * 8 + h) * 2;
        ms[s] = MLpart[mb];
        ls[s] = MLpart[mb + 1];
        mg = fmaxf(mg, ms[s]);
    }
    float lsum = 0.f, osum = 0.f;
    #pragma unroll
    for (int s = 0; s < FL_SPLITS; s++) {
        float w = __expf(ms[s] - mg);
        lsum += ls[s] * w;
        osum += Opart[((long)s * 2500 + q) * 256 + d] * w;
    }
    O[(long)q * 256 + d] = osum / lsum;
}

// ---------------- masked softmax over 192 deformable-attn logits ----------------
__global__ __launch_bounds__(64) void scasoftmax_k(float* __restrict__ logits, const int* __restrict__ valid)
{
    int q = blockIdx.x, lane = threadIdx.x;
    float v[3]; int mk[3];
    #pragma unroll
    for (int i = 0; i < 3; i++) {
        int idx = i * 64 + lane;
        int c = idx >> 5;
        mk[i] = valid[q * 6 + c];
        v[i] = mk[i] ? logits[(long)q * 192 + idx] : -1e30f;
    }
    float mx = fmaxf(fmaxf(v[0], v[1]), v[2]);
    #pragma unroll
    for (int o = 32; o > 0; o >>= 1) mx = fmaxf(mx, __shfl_xor(mx, o, 64));
    float e[3]; float s = 0.f;
    #pragma unroll
    for (int i = 0; i < 3; i++) { e[i] = expf(v[i] - mx); s += e[i]; }
    #pragma unroll
    for (int o = 32; o > 0; o >>= 1) s += __shfl_xor(s, o, 64);
    float inv = 1.f / s;
    #pragma unroll
    for (int i = 0; i < 3; i++)
        logits[(long)q * 192 + i * 64 + lane] = mk[i] ? e[i] * inv : 0.f;
}

// ---------------- deformable sampling ----------------
__global__ __launch_bounds__(256) void sample_k(const float* __restrict__ vals,  // (6,1400,256) hwd
                                                const float* __restrict__ offs,  // (2500,384)
                                                const float* __restrict__ wts,   // (2500,192)
                                                const float* __restrict__ refp,  // (2500,6,2)
                                                const int* __restrict__ valid,   // (2500,6)
                                                float* __restrict__ out)         // (2500,256)
{
    int q = blockIdx.x, d = threadIdx.x;
    __shared__ float s_cw[32][4];
    __shared__ int   s_idx[32][4];
    float acc = 0.f;
    for (int c = 0; c < 6; c++) {
        if (!valid[q * 6 + c]) continue;  // block-uniform branch
        __syncthreads();
        if (d < 32) {
            float ox = offs[(long)q * 384 + (c * 32 + d) * 2 + 0];
            float oy = offs[(long)q * 384 + (c * 32 + d) * 2 + 1];
            float px = refp[(q * 6 + c) * 2 + 0] + ox * (2.f / 49.f);
            float py = refp[(q * 6 + c) * 2 + 1] + oy * (2.f / 27.f);
            float gx = (px + 1.f) * 0.5f * 49.f;
            float gy = (py + 1.f) * 0.5f * 27.f;
            float x0f = floorf(gx), y0f = floorf(gy);
            float wx = gx - x0f, wy = gy - y0f;
            int x0 = (int)x0f, y0 = (int)y0f;
            float wgt = wts[(long)q * 192 + c * 32 + d];
            float cw[4] = {(1.f - wx) * (1.f - wy), wx * (1.f - wy), (1.f - wx) * wy, wx * wy};
            const int dxs[4] = {0, 1, 0, 1};
            const int dys[4] = {0, 0, 1, 1};
            #pragma unroll
            for (int k2 = 0; k2 < 4; k2++) {
                int xi = x0 + dxs[k2], yi = y0 + dys[k2];
                bool ok = (xi >= 0) && (xi < 50) && (yi >= 0) && (yi < 28);
                s_cw[d][k2]  = ok ? cw[k2] * wgt : 0.f;
                s_idx[d][k2] = ok ? (yi * 50 + xi) * 256 : 0;
            }
        }
        __syncthreads();
        const float* vb = vals + (long)c * 358400 + d;
        for (int pt = 0; pt < 32; pt++) {
            #pragma unroll
            for (int k2 = 0; k2 < 4; k2++) {
                float cwv = s_cw[pt][k2];
                if (cwv != 0.f) acc += cwv * vb[s_idx[pt][k2]];
            }
        }
    }
    out[(long)q * 256 + d] = acc;
}

// =====================================================================================
extern "C" void kernel_launch(void* const* d_in, const int* in_sizes, int n_in,
                              void* d_out, int out_size, void* d_ws, size_t ws_size,
                              hipStream_t stream)
{
    const float* images = (const float*)d_in[0];
    const float* intr   = (const float*)d_in[1];
    const float* e2c    = (const float*)d_in[2];
    const float* bevq   = (const float*)d_in[3];
    const float* bevp   = (const float*)d_in[4];
    const float* bbw[5]    = {(const float*)d_in[5],  (const float*)d_in[9],  (const float*)d_in[13], (const float*)d_in[17], (const float*)d_in[21]};
    const float* bbb[5]    = {(const float*)d_in[6],  (const float*)d_in[10], (const float*)d_in[14], (const float*)d_in[18], (const float*)d_in[22]};
    const float* bbg[5]    = {(const float*)d_in[7],  (const float*)d_in[11], (const float*)d_in[15], (const float*)d_in[19], (const float*)d_in[23]};
    const float* bbbeta[5] = {(const float*)d_in[8],  (const float*)d_in[12], (const float*)d_in[16], (const float*)d_in[20], (const float*)d_in[24]};
    const float* sa_wq = (const float*)d_in[25]; const float* sa_bq = (const float*)d_in[26];
    const float* sa_wk = (const float*)d_in[27]; const float* sa_bk = (const float*)d_in[28];
    const float* sa_wv = (const float*)d_in[29]; const float* sa_bv = (const float*)d_in[30];
    const float* sa_wo = (const float*)d_in[31]; const float* sa_bo = (const float*)d_in[32];
    const float* ln1g = (const float*)d_in[33]; const float* ln1b = (const float*)d_in[34];
    const float* ln2g = (const float*)d_in[35]; const float* ln2b = (const float*)d_in[36];
    const float* ln3g = (const float*)d_in[37]; const float* ln3b = (const float*)d_in[38];
    const float* offw = (const float*)d_in[39]; const float* offb = (const float*)d_in[40];
    const float* wtw  = (const float*)d_in[41]; const float* wtb  = (const float*)d_in[42];
    const float* valw = (const float*)d_in[43]; const float* valb = (const float*)d_in[44];
    const float* outw = (const float*)d_in[45]; const float* outb = (const float*)d_in[46];
    const float* fw1  = (const float*)d_in[47]; const float* fb1  = (const float*)d_in[48];
    const float* fw2  = (const float*)d_in[49]; const float* fb2  = (const float*)d_in[50];

    float* ws = (float*)d_ws;
    float* bbA   = ws;            ws += 5734400;   // conv0 out / flash Opart (3.2M) during transformer
    float* bbB   = ws;            ws += 2867200;   // conv1 out / flash MLpart during transformer
    float* feats = ws;            ws += 2150400;   // (6,1400,256) hwd
    float* valsb = ws;            ws += 2150400;   // (6,1400,256) hwd
    float* qbuf  = ws;            ws += 640000;
    float* xq    = ws;            ws += 640000;
    float* bQ    = ws;            ws += 640000;
    float* bK    = ws;            ws += 640000;
    float* bV    = ws;            ws += 640000;
    float* bO    = ws;            ws += 640000;
    float* bH    = ws;            ws += 2560000;   // ffn hidden / offsets
    float* bW    = ws;            ws += 480000;    // logits/weights (2500,192)
    float* refp  = ws;            ws += 30016;
    int*   validb = (int*)ws;     ws += 15040;
    float* stats = ws;            ws += 64;

    auto gemm = [&](const float* A, long ars, long aks, const float* B, long bks, long bns,
                    const float* bias, const float* resid, float* C, int M, int N, int K, int act) {
        dim3 g(N / 64, (M + 63) / 64);
        gemm_k<<<g, 256, 0, stream>>>(A, ars, aks, B, bks, bns, bias, resid, C, M, N, K, act);
    };
    auto conv = [&](const float* in, const float* w, const float* bias, float* out,
                    int Cin, int Cout, int Hin, int Win) {
        int HWo = (Hin >> 1) * (Win >> 1);
        dim3 g((HWo + 63) / 64, Cout / 64);
        conv_gemm_k<<<g, 256, 0, stream>>>(in, w, bias, out, Cin, Cout, Hin, Win);
    };

    // ---- projection of BEV grid ----
    project_k<<<(15000 + 255) / 256, 256, 0, stream>>>(intr, e2c, refp, validb);

    // ---- backbone, per camera ----
    for (int c = 0; c < 6; c++) {
        const float* img = images + (long)c * 3 * 448 * 800;
        conv(img, bbw[0], bbb[0], bbA, 3, 64, 448, 800);
        gn_stats_k<<<32, 256, 0, stream>>>(bbA, (long)2 * 224 * 400, stats);
        gn_apply_k<<<(5734400 + 255) / 256, 256, 0, stream>>>(bbA, bbg[0], bbbeta[0], stats, 224 * 400, 2, 5734400, 1);

        conv(bbA, bbw[1], bbb[1], bbB, 64, 128, 224, 400);
        gn_stats_k<<<32, 256, 0, stream>>>(bbB, (long)4 * 112 * 200, stats);
        gn_apply_k<<<(2867200 + 255) / 256, 256, 0, stream>>>(bbB, bbg[1], bbbeta[1], stats, 112 * 200, 4, 2867200, 1);

        conv(bbB, bbw[2], bbb[2], bbA, 128, 256, 112, 200);
        gn_stats_k<<<32, 256, 0, stream>>>(bbA, (long)8 * 56 * 100, stats);
        gn_apply_k<<<(1433600 + 255) / 256, 256, 0, stream>>>(bbA, bbg[2], bbbeta[2], stats, 56 * 100, 8, 1433600, 1);

        conv(bbA, bbw[3], bbb[3], bbB, 256, 256, 56, 100);
        gn_stats_k<<<32, 256, 0, stream>>>(bbB, (long)8 * 28 * 50, stats);
        gn_apply_k<<<(358400 + 255) / 256, 256, 0, stream>>>(bbB, bbg[3], bbbeta[3], stats, 28 * 50, 8, 358400, 1);

        gemm(bbB, 1, 1400, bbw[4], 1, 256, bbb[4], nullptr, feats + (long)c * 358400, 1400, 256, 256, 0);
        gn_stats_hwd_k<<<32, 256, 0, stream>>>(feats + (long)c * 358400, stats);
        gn_apply_hwd_k<<<1400, 256, 0, stream>>>(feats + (long)c * 358400, bbg[4], bbbeta[4], stats);
    }

    // ---- transformer ----
    qinit_k<<<2500, 256, 0, stream>>>(bevq, bevp, qbuf);

    for (int l = 0; l < 2; l++) {
        long o2 = (long)l * 65536, o1 = (long)l * 256;

        // self-attention
        ln_k<<<625, 256, 0, stream>>>(qbuf, ln1g + o1, ln1b + o1, xq);
        gemm(xq, 256, 1, sa_wq + o2, 256, 1, sa_bq + o1, nullptr, bQ, 2500, 256, 256, 0);
        gemm(xq, 256, 1, sa_wk + o2, 256, 1, sa_bk + o1, nullptr, bK, 2500, 256, 256, 0);
        gemm(xq, 256, 1, sa_wv + o2, 256, 1, sa_bv + o1, nullptr, bV, 2500, 256, 256, 0);
        flash2_k<<<dim3(40, 8, FL_SPLITS), 256, 0, stream>>>(bQ, bK, bV, bbA, bbB);
        flashmerge_k<<<2500, 256, 0, stream>>>(bbA, bbB, bO);
        gemm(bO, 256, 1, sa_wo + o2, 256, 1, sa_bo + o1, qbuf, qbuf, 2500, 256, 256, 0);

        // spatial cross-attention
        ln_k<<<625, 256, 0, stream>>>(qbuf, ln2g + o1, ln2b + o1, xq);
        gemm(feats, 256, 1, valw + o2, 256, 1, valb + o1, nullptr, valsb, 8400, 256, 256, 0);
        gemm(xq, 256, 1, offw + (long)l * 256 * 384, 384, 1, offb + (long)l * 384, nullptr, bH, 2500, 384, 256, 0);
        gemm(xq, 256, 1, wtw + (long)l * 256 * 192, 192, 1, wtb + (long)l * 192, nullptr, bW, 2500, 192, 256, 0);
        scasoftmax_k<<<2500, 64, 0, stream>>>(bW, validb);
        sample_k<<<2500, 256, 0, stream>>>(valsb, bH, bW, refp, validb, bO);
        gemm(bO, 256, 1, outw + o2, 256, 1, outb + o1, qbuf, qbuf, 2500, 256, 256, 0);

        // FFN
        ln_k<<<625, 256, 0, stream>>>(qbuf, ln3g + o1, ln3b + o1, xq);
        gemm(xq, 256, 1, fw1 + (long)l * 262144, 1024, 1, fb1 + (long)l * 1024, nullptr, bH, 2500, 1024, 256, 2);
        gemm(bH, 1024, 1, fw2 + (long)l * 262144, 256, 1, fb2 + o1, qbuf,
             (l == 1) ? (float*)d_out : qbuf, 2500, 256, 1024, 0);
    }
}